// Round 1
// baseline (2729.991 us; speedup 1.0000x reference)
//
#include <hip/hip_runtime.h>
#include <math.h>

// Problem constants (from reference setup_inputs)
#define B_BATCH 2
#define T_SEQ   2048
#define E_DIM   1024
#define H_HEADS 16
#define D_HEAD  64
#define F_DIM   4096
#define M_ROWS  (B_BATCH * T_SEQ)   // 4096

__device__ __forceinline__ float waveReduceSum(float v) {
#pragma unroll
    for (int off = 32; off > 0; off >>= 1) v += __shfl_xor(v, off, 64);
    return v;
}

// ---------------- LayerNorm: one block per row (E=1024, 256 thr, float4) ----
__global__ __launch_bounds__(256) void ln_kernel(const float* __restrict__ x,
                                                 const float* __restrict__ g,
                                                 const float* __restrict__ b,
                                                 float* __restrict__ out) {
    const int row = blockIdx.x;
    const float* xr = x + (size_t)row * E_DIM;
    float4 v = ((const float4*)xr)[threadIdx.x];
    float s  = v.x + v.y + v.z + v.w;
    float sq = v.x * v.x + v.y * v.y + v.z * v.z + v.w * v.w;

    __shared__ float red[8];
    float ws_ = waveReduceSum(s);
    float wq  = waveReduceSum(sq);
    int wid = threadIdx.x >> 6;
    if ((threadIdx.x & 63) == 0) { red[wid] = ws_; red[wid + 4] = wq; }
    __syncthreads();
    float ts = red[0] + red[1] + red[2] + red[3];
    float tq = red[4] + red[5] + red[6] + red[7];
    float mean = ts * (1.0f / E_DIM);
    float var  = tq * (1.0f / E_DIM) - mean * mean;
    float inv  = rsqrtf(var + 1e-5f);

    float4 gv = ((const float4*)g)[threadIdx.x];
    float4 bv = ((const float4*)b)[threadIdx.x];
    float4 o;
    o.x = (v.x - mean) * inv * gv.x + bv.x;
    o.y = (v.y - mean) * inv * gv.y + bv.y;
    o.z = (v.z - mean) * inv * gv.z + bv.z;
    o.w = (v.w - mean) * inv * gv.w + bv.w;
    ((float4*)(out + (size_t)row * E_DIM))[threadIdx.x] = o;
}

// ---------------- SGEMM: C[M,N] = A[M,K] @ W[N,K]^T, fused epilogues --------
// EPI: 0 = plain store, 1 = store acc + R, 2 = store gelu_exact(acc), 3 = C += acc
template <int EPI>
__global__ __launch_bounds__(256) void sgemm_kernel(const float* __restrict__ A,
                                                    const float* __restrict__ Wt,
                                                    const float* __restrict__ R,
                                                    float* __restrict__ C,
                                                    int M, int N, int K) {
    __shared__ float As[8][128];
    __shared__ float Bs[8][128];
    const int tid = threadIdx.x;
    const int tx = tid & 15, ty = tid >> 4;
    const int m0 = blockIdx.y * 128, n0 = blockIdx.x * 128;
    const int lr = tid >> 1;        // 0..127
    const int lk = (tid & 1) * 4;   // 0 or 4
    const float* Aptr = A  + (size_t)(m0 + lr) * K + lk;
    const float* Bptr = Wt + (size_t)(n0 + lr) * K + lk;

    float acc[8][8] = {};

    for (int k0 = 0; k0 < K; k0 += 8) {
        float4 a4 = *(const float4*)(Aptr + k0);
        float4 b4 = *(const float4*)(Bptr + k0);
        __syncthreads();
        As[lk + 0][lr] = a4.x; As[lk + 1][lr] = a4.y;
        As[lk + 2][lr] = a4.z; As[lk + 3][lr] = a4.w;
        Bs[lk + 0][lr] = b4.x; Bs[lk + 1][lr] = b4.y;
        Bs[lk + 2][lr] = b4.z; Bs[lk + 3][lr] = b4.w;
        __syncthreads();
#pragma unroll
        for (int k = 0; k < 8; ++k) {
            float4 a0 = *(const float4*)&As[k][ty * 8];
            float4 a1 = *(const float4*)&As[k][ty * 8 + 4];
            float4 b0 = *(const float4*)&Bs[k][tx * 8];
            float4 b1 = *(const float4*)&Bs[k][tx * 8 + 4];
            float ar[8] = {a0.x, a0.y, a0.z, a0.w, a1.x, a1.y, a1.z, a1.w};
            float br[8] = {b0.x, b0.y, b0.z, b0.w, b1.x, b1.y, b1.z, b1.w};
#pragma unroll
            for (int i = 0; i < 8; ++i)
#pragma unroll
                for (int j = 0; j < 8; ++j) acc[i][j] += ar[i] * br[j];
        }
    }

#pragma unroll
    for (int i = 0; i < 8; ++i) {
        const int row = m0 + ty * 8 + i;
#pragma unroll
        for (int j = 0; j < 8; ++j) {
            const int col = n0 + tx * 8 + j;
            const size_t idx = (size_t)row * N + col;
            float v = acc[i][j];
            if (EPI == 0) {
                C[idx] = v;
            } else if (EPI == 1) {
                C[idx] = v + R[idx];
            } else if (EPI == 2) {
                C[idx] = 0.5f * v * (1.0f + erff(v * 0.70710678118654752f));
            } else {
                C[idx] += v;
            }
        }
    }
}

// ---------------- RoPE + QKV reshape: (B,T,3,H,D) -> q/k/v in (B,H,T,D) ----
__global__ __launch_bounds__(256) void rope_kernel(const float* __restrict__ proj,
                                                   float* __restrict__ qr,
                                                   float* __restrict__ kr,
                                                   float* __restrict__ vr) {
    const int flat = blockIdx.x * 4 + (threadIdx.x >> 6); // (b*T + t)*H + h
    const int lane = threadIdx.x & 63;                    // d
    const int h  = flat % H_HEADS;
    const int bt = flat / H_HEADS;
    const int t  = bt % T_SEQ;
    const int b  = bt / T_SEQ;
    const float* rowp = proj + (size_t)bt * 3 * E_DIM + h * D_HEAD;

    const int i = lane >> 1;
    const float ang = (float)t * powf(10000.0f, -(float)i / 32.0f);
    const float c = cosf(ang), s = sinf(ang);
    const int e = lane & ~1;

    float qxr = rowp[e],          qxi = rowp[e + 1];
    float kxr = rowp[E_DIM + e],  kxi = rowp[E_DIM + e + 1];
    float outq = (lane & 1) ? (qxr * s + qxi * c) : (qxr * c - qxi * s);
    float outk = (lane & 1) ? (kxr * s + kxi * c) : (kxr * c - kxi * s);
    float vv = rowp[2 * E_DIM + lane];

    const size_t oidx = ((size_t)(b * H_HEADS + h) * T_SEQ + t) * D_HEAD + lane;
    qr[oidx] = outq;
    kr[oidx] = outk;
    vr[oidx] = vv;
}

// ---------------- Sliding-window attention: one wave per (b,h,t) -----------
__global__ __launch_bounds__(256) void attn_kernel(const float* __restrict__ qr,
                                                   const float* __restrict__ kr,
                                                   const float* __restrict__ vr,
                                                   const int* __restrict__ ctxp,
                                                   float* __restrict__ o) {
    const int ctx  = ctxp[0];
    const int flat = blockIdx.x * 4 + (threadIdx.x >> 6); // (b*H + h)*T + t
    const int lane = threadIdx.x & 63;                    // d
    const int t  = flat % T_SEQ;
    const int bh = flat / T_SEQ;

    const float qd = qr[(size_t)flat * D_HEAD + lane];
    const float* kbase = kr + (size_t)bh * T_SEQ * D_HEAD;
    const float* vbase = vr + (size_t)bh * T_SEQ * D_HEAD;

    int s0 = t - ctx + 1;
    if (s0 < 0) s0 = 0;

    float m = -3.0e38f, l = 0.0f, acc = 0.0f;
    for (int s = s0; s <= t; ++s) {
        float kd = kbase[(size_t)s * D_HEAD + lane];
        float score = waveReduceSum(qd * kd) * 0.125f; // 1/sqrt(64)
        float mn = fmaxf(m, score);
        float al = expf(m - mn);
        float pw = expf(score - mn);
        float vd = vbase[(size_t)s * D_HEAD + lane];
        l   = l * al + pw;
        acc = acc * al + pw * vd;
        m = mn;
    }
    float res = acc / l;
    const int b = bh / H_HEADS, h = bh % H_HEADS;
    o[((size_t)(b * T_SEQ) + t) * E_DIM + h * D_HEAD + lane] = res;
}

// ---------------------------------------------------------------------------
extern "C" void kernel_launch(void* const* d_in, const int* in_sizes, int n_in,
                              void* d_out, int out_size, void* d_ws, size_t ws_size,
                              hipStream_t stream) {
    const float* x          = (const float*)d_in[0];
    const float* in_proj_w  = (const float*)d_in[1];
    const float* out_proj_w = (const float*)d_in[2];
    const float* ln1_g      = (const float*)d_in[3];
    const float* ln1_b      = (const float*)d_in[4];
    const float* ln2_g      = (const float*)d_in[5];
    const float* ln2_b      = (const float*)d_in[6];
    const float* w1         = (const float*)d_in[7];
    const float* w2         = (const float*)d_in[8];
    const int*   ctx        = (const int*)d_in[9];
    float* out = (float*)d_out;
    float* ws  = (float*)d_ws;

    const size_t MEG = 1024u * 1024u;
    float* h1   = ws;               // 4M floats  (also h2 later)
    float* proj = ws + 4 * MEG;     // 12M floats (B,T,3E)
    float* qr_  = ws + 16 * MEG;    // 4M
    float* kr_  = ws + 20 * MEG;    // 4M
    float* vr_  = ws + 24 * MEG;    // 4M
    float* obuf = ws + 28 * MEG;    // 4M
    float* mid  = ws + 4 * MEG;     // 16M floats, reuses proj/qr (dead by then)

    // 1. h1 = LN1(x)
    ln_kernel<<<M_ROWS, 256, 0, stream>>>(x, ln1_g, ln1_b, h1);
    // 2. proj = h1 @ in_proj_w^T   (4096 x 3072 x 1024)
    sgemm_kernel<0><<<dim3(3 * E_DIM / 128, M_ROWS / 128), 256, 0, stream>>>(
        h1, in_proj_w, nullptr, proj, M_ROWS, 3 * E_DIM, E_DIM);
    // 3. RoPE + split to (B,H,T,D)
    rope_kernel<<<M_ROWS * H_HEADS / 4, 256, 0, stream>>>(proj, qr_, kr_, vr_);
    // 4. sliding-window attention -> obuf in (B,T,E)
    attn_kernel<<<M_ROWS * H_HEADS / 4, 256, 0, stream>>>(qr_, kr_, vr_, ctx, obuf);
    // 5. out = x + obuf @ out_proj_w^T   (4096 x 1024 x 1024)
    sgemm_kernel<1><<<dim3(E_DIM / 128, M_ROWS / 128), 256, 0, stream>>>(
        obuf, out_proj_w, x, out, M_ROWS, E_DIM, E_DIM);
    // 6. h2 = LN2(out)
    ln_kernel<<<M_ROWS, 256, 0, stream>>>(out, ln2_g, ln2_b, h1);
    // 7. mid = gelu(h2 @ w1^T)   (4096 x 4096 x 1024)
    sgemm_kernel<2><<<dim3(F_DIM / 128, M_ROWS / 128), 256, 0, stream>>>(
        h1, w1, nullptr, mid, M_ROWS, F_DIM, E_DIM);
    // 8. out += mid @ w2^T       (4096 x 1024 x 4096)
    sgemm_kernel<3><<<dim3(E_DIM / 128, M_ROWS / 128), 256, 0, stream>>>(
        mid, w2, nullptr, out, M_ROWS, E_DIM, F_DIM);
}

// Round 2
// 1714.299 us; speedup vs baseline: 1.5925x; 1.5925x over previous
//
#include <hip/hip_runtime.h>
#include <math.h>

// Problem constants (from reference setup_inputs)
#define B_BATCH 2
#define T_SEQ   2048
#define E_DIM   1024
#define H_HEADS 16
#define D_HEAD  64
#define F_DIM   4096
#define M_ROWS  (B_BATCH * T_SEQ)   // 4096

__device__ __forceinline__ float waveReduceSum(float v) {
#pragma unroll
    for (int off = 32; off > 0; off >>= 1) v += __shfl_xor(v, off, 64);
    return v;
}

// ---------------- LayerNorm: one block per row (E=1024, 256 thr, float4) ----
__global__ __launch_bounds__(256) void ln_kernel(const float* __restrict__ x,
                                                 const float* __restrict__ g,
                                                 const float* __restrict__ b,
                                                 float* __restrict__ out) {
    const int row = blockIdx.x;
    const float* xr = x + (size_t)row * E_DIM;
    float4 v = ((const float4*)xr)[threadIdx.x];
    float s  = v.x + v.y + v.z + v.w;
    float sq = v.x * v.x + v.y * v.y + v.z * v.z + v.w * v.w;

    __shared__ float red[8];
    float ws_ = waveReduceSum(s);
    float wq  = waveReduceSum(sq);
    int wid = threadIdx.x >> 6;
    if ((threadIdx.x & 63) == 0) { red[wid] = ws_; red[wid + 4] = wq; }
    __syncthreads();
    float ts = red[0] + red[1] + red[2] + red[3];
    float tq = red[4] + red[5] + red[6] + red[7];
    float mean = ts * (1.0f / E_DIM);
    float var  = tq * (1.0f / E_DIM) - mean * mean;
    float inv  = rsqrtf(var + 1e-5f);

    float4 gv = ((const float4*)g)[threadIdx.x];
    float4 bv = ((const float4*)b)[threadIdx.x];
    float4 o;
    o.x = (v.x - mean) * inv * gv.x + bv.x;
    o.y = (v.y - mean) * inv * gv.y + bv.y;
    o.z = (v.z - mean) * inv * gv.z + bv.z;
    o.w = (v.w - mean) * inv * gv.w + bv.w;
    ((float4*)(out + (size_t)row * E_DIM))[threadIdx.x] = o;
}

// ---------------- SGEMM: C[M,N] = A[M,K] @ W[N,K]^T, fused epilogues --------
// EPI: 0 = plain store, 1 = store acc + R, 2 = store gelu_exact(acc), 3 = C += acc
template <int EPI>
__global__ __launch_bounds__(256) void sgemm_kernel(const float* __restrict__ A,
                                                    const float* __restrict__ Wt,
                                                    const float* __restrict__ R,
                                                    float* __restrict__ C,
                                                    int M, int N, int K) {
    __shared__ float As[8][128];
    __shared__ float Bs[8][128];
    const int tid = threadIdx.x;
    const int tx = tid & 15, ty = tid >> 4;
    const int m0 = blockIdx.y * 128, n0 = blockIdx.x * 128;
    const int lr = tid >> 1;        // 0..127
    const int lk = (tid & 1) * 4;   // 0 or 4
    const float* Aptr = A  + (size_t)(m0 + lr) * K + lk;
    const float* Bptr = Wt + (size_t)(n0 + lr) * K + lk;

    float acc[8][8] = {};

    for (int k0 = 0; k0 < K; k0 += 8) {
        float4 a4 = *(const float4*)(Aptr + k0);
        float4 b4 = *(const float4*)(Bptr + k0);
        __syncthreads();
        As[lk + 0][lr] = a4.x; As[lk + 1][lr] = a4.y;
        As[lk + 2][lr] = a4.z; As[lk + 3][lr] = a4.w;
        Bs[lk + 0][lr] = b4.x; Bs[lk + 1][lr] = b4.y;
        Bs[lk + 2][lr] = b4.z; Bs[lk + 3][lr] = b4.w;
        __syncthreads();
#pragma unroll
        for (int k = 0; k < 8; ++k) {
            float4 a0 = *(const float4*)&As[k][ty * 8];
            float4 a1 = *(const float4*)&As[k][ty * 8 + 4];
            float4 b0 = *(const float4*)&Bs[k][tx * 8];
            float4 b1 = *(const float4*)&Bs[k][tx * 8 + 4];
            float ar[8] = {a0.x, a0.y, a0.z, a0.w, a1.x, a1.y, a1.z, a1.w};
            float br[8] = {b0.x, b0.y, b0.z, b0.w, b1.x, b1.y, b1.z, b1.w};
#pragma unroll
            for (int i = 0; i < 8; ++i)
#pragma unroll
                for (int j = 0; j < 8; ++j) acc[i][j] += ar[i] * br[j];
        }
    }

#pragma unroll
    for (int i = 0; i < 8; ++i) {
        const int row = m0 + ty * 8 + i;
#pragma unroll
        for (int j = 0; j < 8; ++j) {
            const int col = n0 + tx * 8 + j;
            const size_t idx = (size_t)row * N + col;
            float v = acc[i][j];
            if (EPI == 0) {
                C[idx] = v;
            } else if (EPI == 1) {
                C[idx] = v + R[idx];
            } else if (EPI == 2) {
                C[idx] = 0.5f * v * (1.0f + erff(v * 0.70710678118654752f));
            } else {
                C[idx] += v;
            }
        }
    }
}

// ---------------- RoPE + QKV reshape: (B,T,3,H,D) -> q/k/v in (B,H,T,D) ----
__global__ __launch_bounds__(256) void rope_kernel(const float* __restrict__ proj,
                                                   float* __restrict__ qr,
                                                   float* __restrict__ kr,
                                                   float* __restrict__ vr) {
    const int flat = blockIdx.x * 4 + (threadIdx.x >> 6); // (b*T + t)*H + h
    const int lane = threadIdx.x & 63;                    // d
    const int h  = flat % H_HEADS;
    const int bt = flat / H_HEADS;
    const int t  = bt % T_SEQ;
    const int b  = bt / T_SEQ;
    const float* rowp = proj + (size_t)bt * 3 * E_DIM + h * D_HEAD;

    const int i = lane >> 1;
    const float ang = (float)t * powf(10000.0f, -(float)i / 32.0f);
    const float c = cosf(ang), s = sinf(ang);
    const int e = lane & ~1;

    float qxr = rowp[e],          qxi = rowp[e + 1];
    float kxr = rowp[E_DIM + e],  kxi = rowp[E_DIM + e + 1];
    float outq = (lane & 1) ? (qxr * s + qxi * c) : (qxr * c - qxi * s);
    float outk = (lane & 1) ? (kxr * s + kxi * c) : (kxr * c - kxi * s);
    float vv = rowp[2 * E_DIM + lane];

    const size_t oidx = ((size_t)(b * H_HEADS + h) * T_SEQ + t) * D_HEAD + lane;
    qr[oidx] = outq;
    kr[oidx] = outk;
    vr[oidx] = vv;
}

// ---------------- Sliding-window attention v2 -------------------------------
// One block per (b, h, 64-query tile). 256 threads = 4 threads per query;
// each thread owns a 16-wide d-quarter of q and of the output accumulator.
// K/V staged in LDS in 64-key tiles; scores via 16 FMA + 2 width-4 shuffles.
__global__ __launch_bounds__(256) void attn_kernel(const float* __restrict__ qr,
                                                   const float* __restrict__ kr,
                                                   const float* __restrict__ vr,
                                                   const int* __restrict__ ctxp,
                                                   float* __restrict__ o) {
    __shared__ float Ks[64][64];
    __shared__ float Vs[64][64];

    const int ctx = ctxp[0];
    const int tid = threadIdx.x;
    const int qi  = tid >> 2;          // query within tile: 0..63
    const int qq  = tid & 3;           // d-quarter: 0..3
    const int qd0 = qq * 16;

    const int bh = blockIdx.x >> 5;                 // (b*H + h)
    const int t0 = (blockIdx.x & 31) * 64;          // query tile start
    const int t  = t0 + qi;

    const float* kbase = kr + (size_t)bh * T_SEQ * D_HEAD;
    const float* vbase = vr + (size_t)bh * T_SEQ * D_HEAD;

    // q quarter into registers
    const float* qrow = qr + ((size_t)bh * T_SEQ + t) * D_HEAD + qd0;
    float4 q0 = *(const float4*)(qrow + 0);
    float4 q1 = *(const float4*)(qrow + 4);
    float4 q2 = *(const float4*)(qrow + 8);
    float4 q3 = *(const float4*)(qrow + 12);

    float m = -3.0e38f, l = 0.0f;
    float4 o0 = {0,0,0,0}, o1 = {0,0,0,0}, o2 = {0,0,0,0}, o3 = {0,0,0,0};

    // key-tile range covering windows of all 64 queries in this block
    int first = t0 - (ctx - 1);
    if (first < 0) first = 0;
    const int first_base = first & ~63;

    for (int s_base = first_base; s_base <= t0; s_base += 64) {
        __syncthreads();
        // stage K/V tile (64 keys x 64 d), zero-padded out of range
#pragma unroll
        for (int i = 0; i < 4; ++i) {
            const int c    = tid + 256 * i;   // 0..1023 float4-chunks
            const int srel = c >> 4;
            const int d4   = (c & 15) * 4;
            const int sg   = s_base + srel;
            float4 kv = {0,0,0,0}, vv = {0,0,0,0};
            if (sg >= 0 && sg < T_SEQ) {
                kv = *(const float4*)(kbase + (size_t)sg * D_HEAD + d4);
                vv = *(const float4*)(vbase + (size_t)sg * D_HEAD + d4);
            }
            *(float4*)&Ks[srel][d4] = kv;
            *(float4*)&Vs[srel][d4] = vv;
        }
        __syncthreads();

        for (int j = 0; j < 64; ++j) {
            const int s = s_base + j;
            const int d = t - s;
            if (s < 0 || d < 0 || d >= ctx) continue;  // uniform across the 4-lane group

            const float* krow = &Ks[j][qd0];
            float4 k0 = *(const float4*)(krow + 0);
            float4 k1 = *(const float4*)(krow + 4);
            float4 k2 = *(const float4*)(krow + 8);
            float4 k3 = *(const float4*)(krow + 12);
            float p = q0.x*k0.x + q0.y*k0.y + q0.z*k0.z + q0.w*k0.w
                    + q1.x*k1.x + q1.y*k1.y + q1.z*k1.z + q1.w*k1.w
                    + q2.x*k2.x + q2.y*k2.y + q2.z*k2.z + q2.w*k2.w
                    + q3.x*k3.x + q3.y*k3.y + q3.z*k3.z + q3.w*k3.w;
            p += __shfl_xor(p, 1, 4);
            p += __shfl_xor(p, 2, 4);
            const float score = p * 0.125f;   // 1/sqrt(64)

            const float mn = fmaxf(m, score);
            const float al = __expf(m - mn);
            const float pw = __expf(score - mn);
            m = mn;
            l = l * al + pw;

            const float* vrow = &Vs[j][qd0];
            float4 v0 = *(const float4*)(vrow + 0);
            float4 v1 = *(const float4*)(vrow + 4);
            float4 v2 = *(const float4*)(vrow + 8);
            float4 v3 = *(const float4*)(vrow + 12);
            o0.x = o0.x*al + pw*v0.x; o0.y = o0.y*al + pw*v0.y;
            o0.z = o0.z*al + pw*v0.z; o0.w = o0.w*al + pw*v0.w;
            o1.x = o1.x*al + pw*v1.x; o1.y = o1.y*al + pw*v1.y;
            o1.z = o1.z*al + pw*v1.z; o1.w = o1.w*al + pw*v1.w;
            o2.x = o2.x*al + pw*v2.x; o2.y = o2.y*al + pw*v2.y;
            o2.z = o2.z*al + pw*v2.z; o2.w = o2.w*al + pw*v2.w;
            o3.x = o3.x*al + pw*v3.x; o3.y = o3.y*al + pw*v3.y;
            o3.z = o3.z*al + pw*v3.z; o3.w = o3.w*al + pw*v3.w;
        }
    }

    const float inv_l = 1.0f / l;
    const int b = bh / H_HEADS, h = bh % H_HEADS;
    float* orow = o + ((size_t)(b * T_SEQ) + t) * E_DIM + h * D_HEAD + qd0;
    float4 r0 = {o0.x*inv_l, o0.y*inv_l, o0.z*inv_l, o0.w*inv_l};
    float4 r1 = {o1.x*inv_l, o1.y*inv_l, o1.z*inv_l, o1.w*inv_l};
    float4 r2 = {o2.x*inv_l, o2.y*inv_l, o2.z*inv_l, o2.w*inv_l};
    float4 r3 = {o3.x*inv_l, o3.y*inv_l, o3.z*inv_l, o3.w*inv_l};
    *(float4*)(orow + 0)  = r0;
    *(float4*)(orow + 4)  = r1;
    *(float4*)(orow + 8)  = r2;
    *(float4*)(orow + 12) = r3;
}

// ---------------------------------------------------------------------------
extern "C" void kernel_launch(void* const* d_in, const int* in_sizes, int n_in,
                              void* d_out, int out_size, void* d_ws, size_t ws_size,
                              hipStream_t stream) {
    const float* x          = (const float*)d_in[0];
    const float* in_proj_w  = (const float*)d_in[1];
    const float* out_proj_w = (const float*)d_in[2];
    const float* ln1_g      = (const float*)d_in[3];
    const float* ln1_b      = (const float*)d_in[4];
    const float* ln2_g      = (const float*)d_in[5];
    const float* ln2_b      = (const float*)d_in[6];
    const float* w1         = (const float*)d_in[7];
    const float* w2         = (const float*)d_in[8];
    const int*   ctx        = (const int*)d_in[9];
    float* out = (float*)d_out;
    float* ws  = (float*)d_ws;

    const size_t MEG = 1024u * 1024u;
    float* h1   = ws;               // 4M floats  (also h2 later)
    float* proj = ws + 4 * MEG;     // 12M floats (B,T,3E)
    float* qr_  = ws + 16 * MEG;    // 4M
    float* kr_  = ws + 20 * MEG;    // 4M
    float* vr_  = ws + 24 * MEG;    // 4M
    float* obuf = ws + 28 * MEG;    // 4M
    float* mid  = ws + 4 * MEG;     // 16M floats, reuses proj/qr (dead by then)

    // 1. h1 = LN1(x)
    ln_kernel<<<M_ROWS, 256, 0, stream>>>(x, ln1_g, ln1_b, h1);
    // 2. proj = h1 @ in_proj_w^T   (4096 x 3072 x 1024)
    sgemm_kernel<0><<<dim3(3 * E_DIM / 128, M_ROWS / 128), 256, 0, stream>>>(
        h1, in_proj_w, nullptr, proj, M_ROWS, 3 * E_DIM, E_DIM);
    // 3. RoPE + split to (B,H,T,D)
    rope_kernel<<<M_ROWS * H_HEADS / 4, 256, 0, stream>>>(proj, qr_, kr_, vr_);
    // 4. sliding-window attention -> obuf in (B,T,E)
    attn_kernel<<<B_BATCH * H_HEADS * (T_SEQ / 64), 256, 0, stream>>>(
        qr_, kr_, vr_, ctx, obuf);
    // 5. out = x + obuf @ out_proj_w^T   (4096 x 1024 x 1024)
    sgemm_kernel<1><<<dim3(E_DIM / 128, M_ROWS / 128), 256, 0, stream>>>(
        obuf, out_proj_w, x, out, M_ROWS, E_DIM, E_DIM);
    // 6. h2 = LN2(out)
    ln_kernel<<<M_ROWS, 256, 0, stream>>>(out, ln2_g, ln2_b, h1);
    // 7. mid = gelu(h2 @ w1^T)   (4096 x 4096 x 1024)
    sgemm_kernel<2><<<dim3(F_DIM / 128, M_ROWS / 128), 256, 0, stream>>>(
        h1, w1, nullptr, mid, M_ROWS, F_DIM, E_DIM);
    // 8. out += mid @ w2^T       (4096 x 1024 x 4096)
    sgemm_kernel<3><<<dim3(E_DIM / 128, M_ROWS / 128), 256, 0, stream>>>(
        mid, w2, nullptr, out, M_ROWS, E_DIM, F_DIM);
}

// Round 3
// 514.338 us; speedup vs baseline: 5.3078x; 3.3330x over previous
//
#include <hip/hip_runtime.h>
#include <math.h>

// Problem constants (from reference setup_inputs)
#define B_BATCH 2
#define T_SEQ   2048
#define E_DIM   1024
#define H_HEADS 16
#define D_HEAD  64
#define F_DIM   4096
#define M_ROWS  (B_BATCH * T_SEQ)   // 4096

typedef __attribute__((ext_vector_type(8))) short short8;       // bf16x8 MFMA frag
typedef __attribute__((ext_vector_type(4))) float floatx4;      // MFMA acc
typedef __attribute__((ext_vector_type(8))) unsigned short ushortx8;

typedef __attribute__((address_space(1))) const void global_cvoid;
typedef __attribute__((address_space(3))) void lds_void;

__device__ __forceinline__ unsigned short f2bf(float f) {      // RNE f32->bf16
    unsigned u = __float_as_uint(f);
    u += 0x7fffu + ((u >> 16) & 1u);
    return (unsigned short)(u >> 16);
}
__device__ __forceinline__ float bf2f(unsigned short h) {
    return __uint_as_float(((unsigned)h) << 16);
}

__device__ __forceinline__ float waveReduceSum(float v) {
#pragma unroll
    for (int off = 32; off > 0; off >>= 1) v += __shfl_xor(v, off, 64);
    return v;
}

// ---------------- fp32 -> bf16 convert (weights), n % 1024 == 0 ------------
__global__ __launch_bounds__(256) void cvt_kernel(const float* __restrict__ in,
                                                  unsigned short* __restrict__ out,
                                                  int n) {
    const int i = (blockIdx.x * 256 + threadIdx.x) * 4;
    if (i >= n) return;
    float4 v = *(const float4*)(in + i);
    ushort4 o;
    o.x = f2bf(v.x); o.y = f2bf(v.y); o.z = f2bf(v.z); o.w = f2bf(v.w);
    *(ushort4*)(out + i) = o;
}

// ---------------- LayerNorm: fp32 in, bf16 out ------------------------------
__global__ __launch_bounds__(256) void ln_kernel(const float* __restrict__ x,
                                                 const float* __restrict__ g,
                                                 const float* __restrict__ b,
                                                 unsigned short* __restrict__ out) {
    const int row = blockIdx.x;
    const float* xr = x + (size_t)row * E_DIM;
    float4 v = ((const float4*)xr)[threadIdx.x];
    float s  = v.x + v.y + v.z + v.w;
    float sq = v.x * v.x + v.y * v.y + v.z * v.z + v.w * v.w;

    __shared__ float red[8];
    float ws_ = waveReduceSum(s);
    float wq  = waveReduceSum(sq);
    int wid = threadIdx.x >> 6;
    if ((threadIdx.x & 63) == 0) { red[wid] = ws_; red[wid + 4] = wq; }
    __syncthreads();
    float ts = red[0] + red[1] + red[2] + red[3];
    float tq = red[4] + red[5] + red[6] + red[7];
    float mean = ts * (1.0f / E_DIM);
    float var  = tq * (1.0f / E_DIM) - mean * mean;
    float inv  = rsqrtf(var + 1e-5f);

    float4 gv = ((const float4*)g)[threadIdx.x];
    float4 bv = ((const float4*)b)[threadIdx.x];
    ushort4 o;
    o.x = f2bf((v.x - mean) * inv * gv.x + bv.x);
    o.y = f2bf((v.y - mean) * inv * gv.y + bv.y);
    o.z = f2bf((v.z - mean) * inv * gv.z + bv.z);
    o.w = f2bf((v.w - mean) * inv * gv.w + bv.w);
    ((ushort4*)(out + (size_t)row * E_DIM))[threadIdx.x] = o;
}

// ---------------- bf16 MFMA GEMM: C[M,N] = A[M,K] @ W[N,K]^T ----------------
// 128x128 block tile, BK=64, 4 waves of 64x64 (4x4 tiles of 16x16x32 MFMA).
// global_load_lds width-16 staging with XOR chunk-swizzle (row of 64 bf16 =
// 8 x 16B chunks; logical chunk q of row r lives at phys chunk q ^ (r&7)) so
// fragment ds_read_b128 is 2-way-per-bank (free) instead of 16-way.
// EPI: 0 = fp32 store, 1 = fp32 store acc+R, 2 = bf16 store gelu(acc),
//      3 = fp32 C += acc
template <int EPI>
__global__ __launch_bounds__(256) void gemm_bf16(const unsigned short* __restrict__ A,
                                                 const unsigned short* __restrict__ Wt,
                                                 const float* __restrict__ R,
                                                 float* __restrict__ Cf,
                                                 unsigned short* __restrict__ Cb,
                                                 int M, int N, int K) {
    __shared__ unsigned short As[128 * 64];
    __shared__ unsigned short Bs[128 * 64];
    const int tid  = threadIdx.x;
    const int wave = tid >> 6, lane = tid & 63;
    const int wm   = wave >> 1, wn = wave & 1;
    const int quad = lane >> 4, l16 = lane & 15;
    const int m0 = blockIdx.y * 128, n0 = blockIdx.x * 128;

    const int row_rel = lane >> 3;   // 0..7: row within 8-row DMA chunk
    const int ch      = lane & 7;    // phys 16B chunk within row

    const floatx4 z = {0.0f, 0.0f, 0.0f, 0.0f};
    floatx4 acc[4][4];
#pragma unroll
    for (int i = 0; i < 4; ++i)
#pragma unroll
        for (int j = 0; j < 4; ++j) acc[i][j] = z;

    for (int k0 = 0; k0 < K; k0 += 64) {
        __syncthreads();
#pragma unroll
        for (int i = 0; i < 4; ++i) {
            const int chunk = wave * 4 + i;          // 0..15 (8 rows each)
            const int grow  = chunk * 8 + row_rel;   // tile row 0..127
            const int lch   = ch ^ (grow & 7);       // swizzled source chunk
            const unsigned short* ga = A  + (size_t)(m0 + grow) * K + k0 + lch * 8;
            const unsigned short* gb = Wt + (size_t)(n0 + grow) * K + k0 + lch * 8;
            __builtin_amdgcn_global_load_lds((global_cvoid*)ga,
                                             (lds_void*)(As + chunk * 512), 16, 0, 0);
            __builtin_amdgcn_global_load_lds((global_cvoid*)gb,
                                             (lds_void*)(Bs + chunk * 512), 16, 0, 0);
        }
        __syncthreads();

#pragma unroll
        for (int ks = 0; ks < 2; ++ks) {
            short8 af[4], bfr[4];
#pragma unroll
            for (int mt = 0; mt < 4; ++mt) {
                const int r = wm * 64 + mt * 16 + l16;
                const int p = (ks * 4 + quad) ^ (r & 7);
                af[mt] = *(const short8*)(As + r * 64 + p * 8);
            }
#pragma unroll
            for (int nt = 0; nt < 4; ++nt) {
                const int r = wn * 64 + nt * 16 + l16;
                const int p = (ks * 4 + quad) ^ (r & 7);
                bfr[nt] = *(const short8*)(Bs + r * 64 + p * 8);
            }
#pragma unroll
            for (int mt = 0; mt < 4; ++mt)
#pragma unroll
                for (int nt = 0; nt < 4; ++nt)
                    acc[mt][nt] = __builtin_amdgcn_mfma_f32_16x16x32_bf16(
                        af[mt], bfr[nt], acc[mt][nt], 0, 0, 0);
        }
    }

    // Epilogue. C/D layout: col = lane&15, row = quad*4 + reg  [m89-verified]
#pragma unroll
    for (int mt = 0; mt < 4; ++mt) {
        const int rb = m0 + wm * 64 + mt * 16 + quad * 4;
#pragma unroll
        for (int nt = 0; nt < 4; ++nt) {
            const int col = n0 + wn * 64 + nt * 16 + l16;
#pragma unroll
            for (int r = 0; r < 4; ++r) {
                const size_t idx = (size_t)(rb + r) * N + col;
                const float v = acc[mt][nt][r];
                if (EPI == 0) {
                    Cf[idx] = v;
                } else if (EPI == 1) {
                    Cf[idx] = v + R[idx];
                } else if (EPI == 2) {
                    Cb[idx] = f2bf(0.5f * v * (1.0f + erff(v * 0.70710678118654752f)));
                } else {
                    Cf[idx] += v;
                }
            }
        }
    }
}

// ---------------- RoPE + QKV reshape: proj fp32 -> q/k/v bf16 (B,H,T,D) ----
__global__ __launch_bounds__(256) void rope_kernel(const float* __restrict__ proj,
                                                   unsigned short* __restrict__ qr,
                                                   unsigned short* __restrict__ kr,
                                                   unsigned short* __restrict__ vr) {
    const int flat = blockIdx.x * 4 + (threadIdx.x >> 6); // (b*T + t)*H + h
    const int lane = threadIdx.x & 63;                    // d
    const int h  = flat % H_HEADS;
    const int bt = flat / H_HEADS;
    const int t  = bt % T_SEQ;
    const int b  = bt / T_SEQ;
    const float* rowp = proj + (size_t)bt * 3 * E_DIM + h * D_HEAD;

    const int i = lane >> 1;
    const float ang = (float)t * powf(10000.0f, -(float)i / 32.0f);
    const float c = cosf(ang), s = sinf(ang);
    const int e = lane & ~1;

    float qxr = rowp[e],          qxi = rowp[e + 1];
    float kxr = rowp[E_DIM + e],  kxi = rowp[E_DIM + e + 1];
    float outq = (lane & 1) ? (qxr * s + qxi * c) : (qxr * c - qxi * s);
    float outk = (lane & 1) ? (kxr * s + kxi * c) : (kxr * c - kxi * s);
    float vv = rowp[2 * E_DIM + lane];

    const size_t oidx = ((size_t)(b * H_HEADS + h) * T_SEQ + t) * D_HEAD + lane;
    qr[oidx] = f2bf(outq);
    kr[oidx] = f2bf(outk);
    vr[oidx] = f2bf(vv);
}

// ---------------- Sliding-window attention (bf16 in, bf16 out) --------------
// One block per (b, h, 64-query tile); 4 threads per query own d-quarters.
__global__ __launch_bounds__(256) void attn_kernel(const unsigned short* __restrict__ qr,
                                                   const unsigned short* __restrict__ kr,
                                                   const unsigned short* __restrict__ vr,
                                                   const int* __restrict__ ctxp,
                                                   unsigned short* __restrict__ o) {
    __shared__ float Ks[64][64];
    __shared__ float Vs[64][64];

    const int ctx = ctxp[0];
    const int tid = threadIdx.x;
    const int qi  = tid >> 2;          // query within tile: 0..63
    const int qq  = tid & 3;           // d-quarter: 0..3
    const int qd0 = qq * 16;

    const int bh = blockIdx.x >> 5;                 // (b*H + h)
    const int t0 = (blockIdx.x & 31) * 64;          // query tile start
    const int t  = t0 + qi;

    const unsigned short* kbase = kr + (size_t)bh * T_SEQ * D_HEAD;
    const unsigned short* vbase = vr + (size_t)bh * T_SEQ * D_HEAD;

    // q quarter -> fp32 registers
    const unsigned short* qrow = qr + ((size_t)bh * T_SEQ + t) * D_HEAD + qd0;
    ushortx8 qa = *(const ushortx8*)(qrow);
    ushortx8 qb = *(const ushortx8*)(qrow + 8);
    float4 q0 = {bf2f(qa[0]), bf2f(qa[1]), bf2f(qa[2]), bf2f(qa[3])};
    float4 q1 = {bf2f(qa[4]), bf2f(qa[5]), bf2f(qa[6]), bf2f(qa[7])};
    float4 q2 = {bf2f(qb[0]), bf2f(qb[1]), bf2f(qb[2]), bf2f(qb[3])};
    float4 q3 = {bf2f(qb[4]), bf2f(qb[5]), bf2f(qb[6]), bf2f(qb[7])};

    float m = -3.0e38f, l = 0.0f;
    float4 o0 = {0,0,0,0}, o1 = {0,0,0,0}, o2 = {0,0,0,0}, o3 = {0,0,0,0};

    int first = t0 - (ctx - 1);
    if (first < 0) first = 0;
    const int first_base = first & ~63;

    for (int s_base = first_base; s_base <= t0; s_base += 64) {
        __syncthreads();
#pragma unroll
        for (int i = 0; i < 2; ++i) {
            const int c    = tid + 256 * i;   // 0..511 ushort8-chunks
            const int srel = c >> 3;
            const int d8   = (c & 7) * 8;
            const int sg   = s_base + srel;
            float4 ka = {0,0,0,0}, kb4 = {0,0,0,0}, va = {0,0,0,0}, vb4 = {0,0,0,0};
            if (sg >= 0 && sg < T_SEQ) {
                ushortx8 kv = *(const ushortx8*)(kbase + (size_t)sg * D_HEAD + d8);
                ushortx8 vv = *(const ushortx8*)(vbase + (size_t)sg * D_HEAD + d8);
                ka  = {bf2f(kv[0]), bf2f(kv[1]), bf2f(kv[2]), bf2f(kv[3])};
                kb4 = {bf2f(kv[4]), bf2f(kv[5]), bf2f(kv[6]), bf2f(kv[7])};
                va  = {bf2f(vv[0]), bf2f(vv[1]), bf2f(vv[2]), bf2f(vv[3])};
                vb4 = {bf2f(vv[4]), bf2f(vv[5]), bf2f(vv[6]), bf2f(vv[7])};
            }
            *(float4*)&Ks[srel][d8]     = ka;
            *(float4*)&Ks[srel][d8 + 4] = kb4;
            *(float4*)&Vs[srel][d8]     = va;
            *(float4*)&Vs[srel][d8 + 4] = vb4;
        }
        __syncthreads();

        for (int j = 0; j < 64; ++j) {
            const int s = s_base + j;
            const int d = t - s;
            if (s < 0 || d < 0 || d >= ctx) continue;  // uniform across 4-lane group

            const float* krow = &Ks[j][qd0];
            float4 k0 = *(const float4*)(krow + 0);
            float4 k1 = *(const float4*)(krow + 4);
            float4 k2 = *(const float4*)(krow + 8);
            float4 k3 = *(const float4*)(krow + 12);
            float p = q0.x*k0.x + q0.y*k0.y + q0.z*k0.z + q0.w*k0.w
                    + q1.x*k1.x + q1.y*k1.y + q1.z*k1.z + q1.w*k1.w
                    + q2.x*k2.x + q2.y*k2.y + q2.z*k2.z + q2.w*k2.w
                    + q3.x*k3.x + q3.y*k3.y + q3.z*k3.z + q3.w*k3.w;
            p += __shfl_xor(p, 1, 4);
            p += __shfl_xor(p, 2, 4);
            const float score = p * 0.125f;   // 1/sqrt(64)

            const float mn = fmaxf(m, score);
            const float al = __expf(m - mn);
            const float pw = __expf(score - mn);
            m = mn;
            l = l * al + pw;

            const float* vrow = &Vs[j][qd0];
            float4 v0 = *(const float4*)(vrow + 0);
            float4 v1 = *(const float4*)(vrow + 4);
            float4 v2 = *(const float4*)(vrow + 8);
            float4 v3 = *(const float4*)(vrow + 12);
            o0.x = o0.x*al + pw*v0.x; o0.y = o0.y*al + pw*v0.y;
            o0.z = o0.z*al + pw*v0.z; o0.w = o0.w*al + pw*v0.w;
            o1.x = o1.x*al + pw*v1.x; o1.y = o1.y*al + pw*v1.y;
            o1.z = o1.z*al + pw*v1.z; o1.w = o1.w*al + pw*v1.w;
            o2.x = o2.x*al + pw*v2.x; o2.y = o2.y*al + pw*v2.y;
            o2.z = o2.z*al + pw*v2.z; o2.w = o2.w*al + pw*v2.w;
            o3.x = o3.x*al + pw*v3.x; o3.y = o3.y*al + pw*v3.y;
            o3.z = o3.z*al + pw*v3.z; o3.w = o3.w*al + pw*v3.w;
        }
    }

    const float inv_l = 1.0f / l;
    const int b = bh / H_HEADS, h = bh % H_HEADS;
    unsigned short* orow = o + ((size_t)(b * T_SEQ) + t) * E_DIM + h * D_HEAD + qd0;
    ushortx8 r0, r1;
    r0[0] = f2bf(o0.x*inv_l); r0[1] = f2bf(o0.y*inv_l);
    r0[2] = f2bf(o0.z*inv_l); r0[3] = f2bf(o0.w*inv_l);
    r0[4] = f2bf(o1.x*inv_l); r0[5] = f2bf(o1.y*inv_l);
    r0[6] = f2bf(o1.z*inv_l); r0[7] = f2bf(o1.w*inv_l);
    r1[0] = f2bf(o2.x*inv_l); r1[1] = f2bf(o2.y*inv_l);
    r1[2] = f2bf(o2.z*inv_l); r1[3] = f2bf(o2.w*inv_l);
    r1[4] = f2bf(o3.x*inv_l); r1[5] = f2bf(o3.y*inv_l);
    r1[6] = f2bf(o3.z*inv_l); r1[7] = f2bf(o3.w*inv_l);
    *(ushortx8*)(orow)     = r0;
    *(ushortx8*)(orow + 8) = r1;
}

// ---------------------------------------------------------------------------
extern "C" void kernel_launch(void* const* d_in, const int* in_sizes, int n_in,
                              void* d_out, int out_size, void* d_ws, size_t ws_size,
                              hipStream_t stream) {
    const float* x          = (const float*)d_in[0];
    const float* in_proj_w  = (const float*)d_in[1];
    const float* out_proj_w = (const float*)d_in[2];
    const float* ln1_g      = (const float*)d_in[3];
    const float* ln1_b      = (const float*)d_in[4];
    const float* ln2_g      = (const float*)d_in[5];
    const float* ln2_b      = (const float*)d_in[6];
    const float* w1         = (const float*)d_in[7];
    const float* w2         = (const float*)d_in[8];
    const int*   ctx        = (const int*)d_in[9];
    float* out = (float*)d_out;
    float* ws  = (float*)d_ws;

    const size_t MEG = 1024u * 1024u;
    unsigned short* u = (unsigned short*)ws;
    // bf16 region (ushort offsets)
    unsigned short* wqkv_b = u;                 // 3M elems
    unsigned short* wout_b = u + 3 * MEG;       // 1M
    unsigned short* w1_b   = u + 4 * MEG;       // 4M
    unsigned short* w2_b   = u + 8 * MEG;       // 4M
    unsigned short* h_b    = u + 12 * MEG;      // 4M (h1, then h2)
    unsigned short* obuf_b = u + 16 * MEG;      // 4M
    unsigned short* q_b    = u + 20 * MEG;      // 4M
    unsigned short* k_b    = u + 24 * MEG;      // 4M
    unsigned short* v_b    = u + 28 * MEG;      // 4M   (ends at 64 MB)
    // fp32 region
    float* proj = ws + 16 * MEG;                // 12M floats [64MB..112MB)
    unsigned short* mid_b = (unsigned short*)(ws + 16 * MEG); // 16M elems, overlays proj (dead)

    // 0. weights -> bf16
    cvt_kernel<<<3 * E_DIM * E_DIM / 1024, 256, 0, stream>>>(in_proj_w, wqkv_b, 3 * E_DIM * E_DIM);
    cvt_kernel<<<E_DIM * E_DIM / 1024, 256, 0, stream>>>(out_proj_w, wout_b, E_DIM * E_DIM);
    cvt_kernel<<<F_DIM * E_DIM / 1024, 256, 0, stream>>>(w1, w1_b, F_DIM * E_DIM);
    cvt_kernel<<<E_DIM * F_DIM / 1024, 256, 0, stream>>>(w2, w2_b, E_DIM * F_DIM);

    // 1. h1 = LN1(x) -> bf16
    ln_kernel<<<M_ROWS, 256, 0, stream>>>(x, ln1_g, ln1_b, h_b);
    // 2. proj = h1 @ in_proj_w^T (fp32 out)
    gemm_bf16<0><<<dim3(3 * E_DIM / 128, M_ROWS / 128), 256, 0, stream>>>(
        h_b, wqkv_b, nullptr, proj, nullptr, M_ROWS, 3 * E_DIM, E_DIM);
    // 3. RoPE + split -> bf16 (B,H,T,D)
    rope_kernel<<<M_ROWS * H_HEADS / 4, 256, 0, stream>>>(proj, q_b, k_b, v_b);
    // 4. attention -> obuf bf16 (B,T,E)
    attn_kernel<<<B_BATCH * H_HEADS * (T_SEQ / 64), 256, 0, stream>>>(
        q_b, k_b, v_b, ctx, obuf_b);
    // 5. out = x + obuf @ out_proj_w^T (fp32)
    gemm_bf16<1><<<dim3(E_DIM / 128, M_ROWS / 128), 256, 0, stream>>>(
        obuf_b, wout_b, x, out, nullptr, M_ROWS, E_DIM, E_DIM);
    // 6. h2 = LN2(out) -> bf16
    ln_kernel<<<M_ROWS, 256, 0, stream>>>(out, ln2_g, ln2_b, h_b);
    // 7. mid = gelu(h2 @ w1^T) -> bf16
    gemm_bf16<2><<<dim3(F_DIM / 128, M_ROWS / 128), 256, 0, stream>>>(
        h_b, w1_b, nullptr, nullptr, mid_b, M_ROWS, F_DIM, E_DIM);
    // 8. out += mid @ w2^T (fp32 rmw)
    gemm_bf16<3><<<dim3(E_DIM / 128, M_ROWS / 128), 256, 0, stream>>>(
        mid_b, w2_b, nullptr, out, nullptr, M_ROWS, E_DIM, F_DIM);
}

// Round 4
// 374.104 us; speedup vs baseline: 7.2974x; 1.3749x over previous
//
#include <hip/hip_runtime.h>
#include <math.h>

// Problem constants (from reference setup_inputs)
#define B_BATCH 2
#define T_SEQ   2048
#define E_DIM   1024
#define H_HEADS 16
#define D_HEAD  64
#define F_DIM   4096
#define M_ROWS  (B_BATCH * T_SEQ)   // 4096

typedef __attribute__((ext_vector_type(8))) short short8;       // bf16x8 MFMA frag
typedef __attribute__((ext_vector_type(4))) float floatx4;      // MFMA acc
typedef __attribute__((ext_vector_type(8))) unsigned short ushortx8;

typedef __attribute__((address_space(1))) const void global_cvoid;
typedef __attribute__((address_space(3))) void lds_void;

__device__ __forceinline__ unsigned short f2bf(float f) {      // RNE f32->bf16
    unsigned u = __float_as_uint(f);
    u += 0x7fffu + ((u >> 16) & 1u);
    return (unsigned short)(u >> 16);
}
__device__ __forceinline__ float bf2f(unsigned short h) {
    return __uint_as_float(((unsigned)h) << 16);
}

__device__ __forceinline__ float waveReduceSum(float v) {
#pragma unroll
    for (int off = 32; off > 0; off >>= 1) v += __shfl_xor(v, off, 64);
    return v;
}

// ---------------- fp32 -> bf16 convert (weights), n % 1024 == 0 ------------
__global__ __launch_bounds__(256) void cvt_kernel(const float* __restrict__ in,
                                                  unsigned short* __restrict__ out,
                                                  int n) {
    const int i = (blockIdx.x * 256 + threadIdx.x) * 4;
    if (i >= n) return;
    float4 v = *(const float4*)(in + i);
    ushort4 o;
    o.x = f2bf(v.x); o.y = f2bf(v.y); o.z = f2bf(v.z); o.w = f2bf(v.w);
    *(ushort4*)(out + i) = o;
}

// ---------------- RoPE cos/sin table: tab[pos*32+i] = {cos, sin} -----------
__global__ __launch_bounds__(256) void rope_tab_kernel(float* __restrict__ tab) {
    const int idx = blockIdx.x * 256 + threadIdx.x;   // 0 .. T*32-1
    const int pos = idx >> 5, i = idx & 31;
    const float invf = powf(10000.0f, -(float)i / 32.0f);
    const float ang = (float)pos * invf;
    tab[idx * 2]     = cosf(ang);
    tab[idx * 2 + 1] = sinf(ang);
}

// ---------------- LayerNorm: fp32 in, bf16 out ------------------------------
__global__ __launch_bounds__(256) void ln_kernel(const float* __restrict__ x,
                                                 const float* __restrict__ g,
                                                 const float* __restrict__ b,
                                                 unsigned short* __restrict__ out) {
    const int row = blockIdx.x;
    const float* xr = x + (size_t)row * E_DIM;
    float4 v = ((const float4*)xr)[threadIdx.x];
    float s  = v.x + v.y + v.z + v.w;
    float sq = v.x * v.x + v.y * v.y + v.z * v.z + v.w * v.w;

    __shared__ float red[8];
    float ws_ = waveReduceSum(s);
    float wq  = waveReduceSum(sq);
    int wid = threadIdx.x >> 6;
    if ((threadIdx.x & 63) == 0) { red[wid] = ws_; red[wid + 4] = wq; }
    __syncthreads();
    float ts = red[0] + red[1] + red[2] + red[3];
    float tq = red[4] + red[5] + red[6] + red[7];
    float mean = ts * (1.0f / E_DIM);
    float var  = tq * (1.0f / E_DIM) - mean * mean;
    float inv  = rsqrtf(var + 1e-5f);

    float4 gv = ((const float4*)g)[threadIdx.x];
    float4 bv = ((const float4*)b)[threadIdx.x];
    ushort4 o;
    o.x = f2bf((v.x - mean) * inv * gv.x + bv.x);
    o.y = f2bf((v.y - mean) * inv * gv.y + bv.y);
    o.z = f2bf((v.z - mean) * inv * gv.z + bv.z);
    o.w = f2bf((v.w - mean) * inv * gv.w + bv.w);
    ((ushort4*)(out + (size_t)row * E_DIM))[threadIdx.x] = o;
}

// ---------------- bf16 MFMA GEMM: C[M,N] = A[M,K] @ W[N,K]^T ----------------
// EPI: 0 = fp32 store, 1 = fp32 store acc+R, 2 = bf16 store gelu(acc),
//      3 = fp32 C += acc, 4 = bf16 store
template <int EPI>
__global__ __launch_bounds__(256) void gemm_bf16(const unsigned short* __restrict__ A,
                                                 const unsigned short* __restrict__ Wt,
                                                 const float* __restrict__ R,
                                                 float* __restrict__ Cf,
                                                 unsigned short* __restrict__ Cb,
                                                 int M, int N, int K) {
    __shared__ unsigned short As[128 * 64];
    __shared__ unsigned short Bs[128 * 64];
    const int tid  = threadIdx.x;
    const int wave = tid >> 6, lane = tid & 63;
    const int wm   = wave >> 1, wn = wave & 1;
    const int quad = lane >> 4, l16 = lane & 15;
    const int m0 = blockIdx.y * 128, n0 = blockIdx.x * 128;

    const int row_rel = lane >> 3;   // 0..7: row within 8-row DMA chunk
    const int ch      = lane & 7;    // phys 16B chunk within row

    const floatx4 z = {0.0f, 0.0f, 0.0f, 0.0f};
    floatx4 acc[4][4];
#pragma unroll
    for (int i = 0; i < 4; ++i)
#pragma unroll
        for (int j = 0; j < 4; ++j) acc[i][j] = z;

    for (int k0 = 0; k0 < K; k0 += 64) {
        __syncthreads();
#pragma unroll
        for (int i = 0; i < 4; ++i) {
            const int chunk = wave * 4 + i;          // 0..15 (8 rows each)
            const int grow  = chunk * 8 + row_rel;   // tile row 0..127
            const int lch   = ch ^ (grow & 7);       // swizzled source chunk
            const unsigned short* ga = A  + (size_t)(m0 + grow) * K + k0 + lch * 8;
            const unsigned short* gb = Wt + (size_t)(n0 + grow) * K + k0 + lch * 8;
            __builtin_amdgcn_global_load_lds((global_cvoid*)ga,
                                             (lds_void*)(As + chunk * 512), 16, 0, 0);
            __builtin_amdgcn_global_load_lds((global_cvoid*)gb,
                                             (lds_void*)(Bs + chunk * 512), 16, 0, 0);
        }
        __syncthreads();

#pragma unroll
        for (int ks = 0; ks < 2; ++ks) {
            short8 af[4], bfr[4];
#pragma unroll
            for (int mt = 0; mt < 4; ++mt) {
                const int r = wm * 64 + mt * 16 + l16;
                const int p = (ks * 4 + quad) ^ (r & 7);
                af[mt] = *(const short8*)(As + r * 64 + p * 8);
            }
#pragma unroll
            for (int nt = 0; nt < 4; ++nt) {
                const int r = wn * 64 + nt * 16 + l16;
                const int p = (ks * 4 + quad) ^ (r & 7);
                bfr[nt] = *(const short8*)(Bs + r * 64 + p * 8);
            }
#pragma unroll
            for (int mt = 0; mt < 4; ++mt)
#pragma unroll
                for (int nt = 0; nt < 4; ++nt)
                    acc[mt][nt] = __builtin_amdgcn_mfma_f32_16x16x32_bf16(
                        af[mt], bfr[nt], acc[mt][nt], 0, 0, 0);
        }
    }

    // Epilogue. C/D layout: col = lane&15, row = quad*4 + reg  [m89-verified]
#pragma unroll
    for (int mt = 0; mt < 4; ++mt) {
        const int rb = m0 + wm * 64 + mt * 16 + quad * 4;
#pragma unroll
        for (int nt = 0; nt < 4; ++nt) {
            const int col = n0 + wn * 64 + nt * 16 + l16;
#pragma unroll
            for (int r = 0; r < 4; ++r) {
                const size_t idx = (size_t)(rb + r) * N + col;
                const float v = acc[mt][nt][r];
                if (EPI == 0) {
                    Cf[idx] = v;
                } else if (EPI == 1) {
                    Cf[idx] = v + R[idx];
                } else if (EPI == 2) {
                    Cb[idx] = f2bf(0.5f * v * (1.0f + erff(v * 0.70710678118654752f)));
                } else if (EPI == 3) {
                    Cf[idx] += v;
                } else {
                    Cb[idx] = f2bf(v);
                }
            }
        }
    }
}

// ---------------- V transpose: proj v-part -> vt[(bh*64+d)][T] bf16 --------
__global__ __launch_bounds__(256) void vtrans_kernel(const unsigned short* __restrict__ proj,
                                                     unsigned short* __restrict__ vt) {
    __shared__ unsigned short L[64 * 72];
    const int bh = blockIdx.y, b = bh >> 4, h = bh & 15;
    const int st = blockIdx.x * 64;
    const int tid = threadIdx.x;
    {
        const int srel = tid >> 2, d16 = (tid & 3) * 16;
        const unsigned short* src =
            proj + (size_t)(b * T_SEQ + st + srel) * (3 * E_DIM) + 2 * E_DIM + h * 64 + d16;
        *(short8*)(L + srel * 72 + d16)     = *(const short8*)(src);
        *(short8*)(L + srel * 72 + d16 + 8) = *(const short8*)(src + 8);
    }
    __syncthreads();
    {
        const int d = tid >> 2, s16 = (tid & 3) * 16;
        short8 o0, o1;
#pragma unroll
        for (int j = 0; j < 8; ++j) {
            o0[j] = (short)L[(s16 + j) * 72 + d];
            o1[j] = (short)L[(s16 + 8 + j) * 72 + d];
        }
        unsigned short* dst = vt + (size_t)(bh * 64 + d) * T_SEQ + st + s16;
        *(short8*)dst       = o0;
        *(short8*)(dst + 8) = o1;
    }
}

// ---------------- Flash attention w/ fused RoPE, MFMA -----------------------
// Block = (b, h, 64-query tile); 4 waves x 16 queries. Key tiles of 64 staged
// in LDS (K with RoPE applied; V^T via global_load_lds w/ XOR swizzle).
// QK^T and PV on MFMA 16x16x32; P round-trips LDS (C-layout -> A-layout).
__device__ __forceinline__ void rope16(ushortx8 x0, ushortx8 x1, const float* tp,
                                       short8& y0, short8& y1) {
#pragma unroll
    for (int j = 0; j < 4; ++j) {
        const float c = tp[2 * j], s = tp[2 * j + 1];
        const float xr = bf2f(x0[2 * j]), xi = bf2f(x0[2 * j + 1]);
        y0[2 * j]     = (short)f2bf(xr * c - xi * s);
        y0[2 * j + 1] = (short)f2bf(xr * s + xi * c);
    }
#pragma unroll
    for (int j = 0; j < 4; ++j) {
        const float c = tp[8 + 2 * j], s = tp[8 + 2 * j + 1];
        const float xr = bf2f(x1[2 * j]), xi = bf2f(x1[2 * j + 1]);
        y1[2 * j]     = (short)f2bf(xr * c - xi * s);
        y1[2 * j + 1] = (short)f2bf(xr * s + xi * c);
    }
}

__global__ __launch_bounds__(256) void attn_kernel(const unsigned short* __restrict__ proj,
                                                   const unsigned short* __restrict__ vt,
                                                   const float* __restrict__ tab,
                                                   const int* __restrict__ ctxp,
                                                   unsigned short* __restrict__ o) {
    __shared__ unsigned short Qs[64 * 64];
    __shared__ unsigned short Ks[64 * 64];
    __shared__ unsigned short Vs[64 * 64];
    __shared__ unsigned short Ps[4][16 * 64];

    const int ctx = ctxp[0];
    const int tid = threadIdx.x;
    const int wave = tid >> 6, lane = tid & 63;
    const int quad = lane >> 4, l16 = lane & 15;
    const int bh = blockIdx.y, b = bh >> 4, h = bh & 15;
    const int t0 = blockIdx.x * 64;

    // ---- stage Q with RoPE (rows swizzled: chunk c at phys c^(row&7)) ----
    {
        const int r = tid >> 2, d16 = (tid & 3) * 16;
        const int pos = t0 + r;
        const unsigned short* src =
            proj + (size_t)(b * T_SEQ + pos) * (3 * E_DIM) + h * 64 + d16;
        ushortx8 x0 = *(const ushortx8*)src;
        ushortx8 x1 = *(const ushortx8*)(src + 8);
        const float* tp = tab + ((size_t)pos * 32 + (d16 >> 1)) * 2;
        short8 y0, y1;
        rope16(x0, x1, tp, y0, y1);
        const int c0 = (tid & 3) * 2;
        *(short8*)(Qs + r * 64 + ((c0)     ^ (r & 7)) * 8) = y0;
        *(short8*)(Qs + r * 64 + ((c0 + 1) ^ (r & 7)) * 8) = y1;
    }

    int first = t0 - (ctx - 1);
    if (first < 0) first = 0;
    const int first_base = first & ~63;

    float m[4] = {-1e30f, -1e30f, -1e30f, -1e30f};
    float l[4] = {0.0f, 0.0f, 0.0f, 0.0f};
    const floatx4 z = {0.0f, 0.0f, 0.0f, 0.0f};
    floatx4 accO[4] = {z, z, z, z};

    const int q_row0 = t0 + wave * 16 + quad * 4;   // abs query of reg r=0

    for (int s_base = first_base; s_base <= t0; s_base += 64) {
        __syncthreads();
        // ---- stage K with RoPE ----
        {
            const int r = tid >> 2, d16 = (tid & 3) * 16;
            const int pos = s_base + r;
            const unsigned short* src =
                proj + (size_t)(b * T_SEQ + pos) * (3 * E_DIM) + E_DIM + h * 64 + d16;
            ushortx8 x0 = *(const ushortx8*)src;
            ushortx8 x1 = *(const ushortx8*)(src + 8);
            const float* tp = tab + ((size_t)pos * 32 + (d16 >> 1)) * 2;
            short8 y0, y1;
            rope16(x0, x1, tp, y0, y1);
            const int c0 = (tid & 3) * 2;
            *(short8*)(Ks + r * 64 + ((c0)     ^ (r & 7)) * 8) = y0;
            *(short8*)(Ks + r * 64 + ((c0 + 1) ^ (r & 7)) * 8) = y1;
        }
        // ---- stage V^T tile via DMA (row d, cols s_base..+63, swizzled) ----
#pragma unroll
        for (int i = 0; i < 2; ++i) {
            const int chunk = (wave * 2 + i) * 64 + lane;   // 0..511
            const int d = chunk >> 3, c = chunk & 7;
            const unsigned short* gsrc =
                vt + (size_t)(bh * 64 + d) * T_SEQ + s_base + ((c ^ (d & 7)) * 8);
            __builtin_amdgcn_global_load_lds((global_cvoid*)gsrc,
                                             (lds_void*)(Vs + (wave * 2 + i) * 512),
                                             16, 0, 0);
        }
        __syncthreads();

        // ---- S = Q K^T (8 MFMA) ----
        floatx4 accS[4] = {z, z, z, z};
#pragma unroll
        for (int ks = 0; ks < 2; ++ks) {
            const int qrow = wave * 16 + l16;
            short8 aq = *(const short8*)(Qs + qrow * 64 + (((ks * 4 + quad) ^ (qrow & 7)) * 8));
#pragma unroll
            for (int nt = 0; nt < 4; ++nt) {
                const int kro = nt * 16 + l16;
                short8 bk = *(const short8*)(Ks + kro * 64 + (((ks * 4 + quad) ^ (kro & 7)) * 8));
                accS[nt] = __builtin_amdgcn_mfma_f32_16x16x32_bf16(aq, bk, accS[nt], 0, 0, 0);
            }
        }

        // ---- mask + online softmax (per q-row r = quad*4+reg) ----
        float p[4][4];      // [nt][r]
        float alpha[4];
#pragma unroll
        for (int r = 0; r < 4; ++r) {
            const int qa = q_row0 + r;
            float sv[4];
            float vmax = -1e30f;
#pragma unroll
            for (int nt = 0; nt < 4; ++nt) {
                const int sa = s_base + nt * 16 + l16;
                const int dd = qa - sa;
                const bool ok = (unsigned)dd < (unsigned)ctx;
                const float s = ok ? accS[nt][r] * 0.125f : -1e30f;
                sv[nt] = s;
                vmax = fmaxf(vmax, s);
            }
            vmax = fmaxf(vmax, __shfl_xor(vmax, 1));
            vmax = fmaxf(vmax, __shfl_xor(vmax, 2));
            vmax = fmaxf(vmax, __shfl_xor(vmax, 4));
            vmax = fmaxf(vmax, __shfl_xor(vmax, 8));
            const float mn = fmaxf(m[r], vmax);
            alpha[r] = __expf(m[r] - mn);
            float ps = 0.0f;
#pragma unroll
            for (int nt = 0; nt < 4; ++nt) {
                const float pe = (sv[nt] > -0.5e30f) ? __expf(sv[nt] - mn) : 0.0f;
                p[nt][r] = pe;
                ps += pe;
            }
            ps += __shfl_xor(ps, 1);
            ps += __shfl_xor(ps, 2);
            ps += __shfl_xor(ps, 4);
            ps += __shfl_xor(ps, 8);
            l[r] = l[r] * alpha[r] + ps;
            m[r] = mn;
        }

        // ---- write P to LDS (C-layout -> A-layout), rescale O ----
#pragma unroll
        for (int nt = 0; nt < 4; ++nt) {
#pragma unroll
            for (int r = 0; r < 4; ++r) {
                const int row = quad * 4 + r;
                const int col = nt * 16 + l16;
                Ps[wave][row * 64 + (((col >> 3) ^ (row & 7)) * 8) + (col & 7)] =
                    f2bf(p[nt][r]);
            }
        }
#pragma unroll
        for (int nt = 0; nt < 4; ++nt)
#pragma unroll
            for (int r = 0; r < 4; ++r) accO[nt][r] *= alpha[r];

        // ---- O += P V (8 MFMA) ----
#pragma unroll
        for (int ks = 0; ks < 2; ++ks) {
            short8 ap = *(const short8*)(&Ps[wave][l16 * 64 + (((ks * 4 + quad) ^ (l16 & 7)) * 8)]);
#pragma unroll
            for (int nt = 0; nt < 4; ++nt) {
                const int dr = nt * 16 + l16;
                short8 bv = *(const short8*)(Vs + dr * 64 + (((ks * 4 + quad) ^ (dr & 7)) * 8));
                accO[nt] = __builtin_amdgcn_mfma_f32_16x16x32_bf16(ap, bv, accO[nt], 0, 0, 0);
            }
        }
    }

    // ---- epilogue: normalize, store bf16 to (B,T,E) ----
    float inv[4];
#pragma unroll
    for (int r = 0; r < 4; ++r) inv[r] = 1.0f / l[r];
#pragma unroll
    for (int nt = 0; nt < 4; ++nt) {
#pragma unroll
        for (int r = 0; r < 4; ++r) {
            const int t = q_row0 + r;
            o[(size_t)(b * T_SEQ + t) * E_DIM + h * 64 + nt * 16 + l16] =
                f2bf(accO[nt][r] * inv[r]);
        }
    }
}

// ---------------------------------------------------------------------------
extern "C" void kernel_launch(void* const* d_in, const int* in_sizes, int n_in,
                              void* d_out, int out_size, void* d_ws, size_t ws_size,
                              hipStream_t stream) {
    const float* x          = (const float*)d_in[0];
    const float* in_proj_w  = (const float*)d_in[1];
    const float* out_proj_w = (const float*)d_in[2];
    const float* ln1_g      = (const float*)d_in[3];
    const float* ln1_b      = (const float*)d_in[4];
    const float* ln2_g      = (const float*)d_in[5];
    const float* ln2_b      = (const float*)d_in[6];
    const float* w1         = (const float*)d_in[7];
    const float* w2         = (const float*)d_in[8];
    const int*   ctx        = (const int*)d_in[9];
    float* out = (float*)d_out;
    float* ws  = (float*)d_ws;

    const size_t MEG = 1024u * 1024u;
    unsigned short* u = (unsigned short*)ws;
    unsigned short* wqkv_b = u;                 // 3M elems
    unsigned short* wout_b = u + 3 * MEG;       // 1M
    unsigned short* w1_b   = u + 4 * MEG;       // 4M
    unsigned short* w2_b   = u + 8 * MEG;       // 4M
    unsigned short* h_b    = u + 12 * MEG;      // 4M (h1, then h2)
    unsigned short* obuf_b = u + 16 * MEG;      // 4M
    unsigned short* proj_b = u + 20 * MEG;      // 12M (B,T,3E bf16)
    unsigned short* vt_b   = u + 32 * MEG;      // 4M  (B*H*64, T) bf16
    unsigned short* mid_b  = u + 36 * MEG;      // 16M (ends at 104 MB)
    float* tab = ws + 26 * MEG;                 // 128K floats (T*32*2) @104MB

    // 0. weights -> bf16; rope table
    cvt_kernel<<<3 * E_DIM * E_DIM / 1024, 256, 0, stream>>>(in_proj_w, wqkv_b, 3 * E_DIM * E_DIM);
    cvt_kernel<<<E_DIM * E_DIM / 1024, 256, 0, stream>>>(out_proj_w, wout_b, E_DIM * E_DIM);
    cvt_kernel<<<F_DIM * E_DIM / 1024, 256, 0, stream>>>(w1, w1_b, F_DIM * E_DIM);
    cvt_kernel<<<E_DIM * F_DIM / 1024, 256, 0, stream>>>(w2, w2_b, E_DIM * F_DIM);
    rope_tab_kernel<<<T_SEQ * 32 / 256, 256, 0, stream>>>(tab);

    // 1. h1 = LN1(x) -> bf16
    ln_kernel<<<M_ROWS, 256, 0, stream>>>(x, ln1_g, ln1_b, h_b);
    // 2. proj = h1 @ in_proj_w^T -> bf16
    gemm_bf16<4><<<dim3(3 * E_DIM / 128, M_ROWS / 128), 256, 0, stream>>>(
        h_b, wqkv_b, nullptr, nullptr, proj_b, M_ROWS, 3 * E_DIM, E_DIM);
    // 3. V^T
    vtrans_kernel<<<dim3(T_SEQ / 64, B_BATCH * H_HEADS), 256, 0, stream>>>(proj_b, vt_b);
    // 4. flash attention (fused RoPE) -> obuf bf16 (B,T,E)
    attn_kernel<<<dim3(T_SEQ / 64, B_BATCH * H_HEADS), 256, 0, stream>>>(
        proj_b, vt_b, tab, ctx, obuf_b);
    // 5. out = x + obuf @ out_proj_w^T (fp32)
    gemm_bf16<1><<<dim3(E_DIM / 128, M_ROWS / 128), 256, 0, stream>>>(
        obuf_b, wout_b, x, out, nullptr, M_ROWS, E_DIM, E_DIM);
    // 6. h2 = LN2(out) -> bf16
    ln_kernel<<<M_ROWS, 256, 0, stream>>>(out, ln2_g, ln2_b, h_b);
    // 7. mid = gelu(h2 @ w1^T) -> bf16
    gemm_bf16<2><<<dim3(F_DIM / 128, M_ROWS / 128), 256, 0, stream>>>(
        h_b, w1_b, nullptr, nullptr, mid_b, M_ROWS, F_DIM, E_DIM);
    // 8. out += mid @ w2^T (fp32 rmw)
    gemm_bf16<3><<<dim3(E_DIM / 128, M_ROWS / 128), 256, 0, stream>>>(
        mid_b, w2_b, nullptr, out, nullptr, M_ROWS, E_DIM, F_DIM);
}